// Round 1
// 9843.811 us; speedup vs baseline: 2.1307x; 2.1307x over previous
//
#include <hip/hip_runtime.h>

// ---------------------------------------------------------------------------
// Persistent weight-stationary LSTM, bf16 MFMA, hand-rolled grid barrier.
// T=1024 B=64 C=256 H=512, 2 layers, fp32 in/out.
//  - 256 blocks x 256 threads, 1 block/CU, co-resident; blocks 0..127 = layer0
//    (step t), 128..255 = layer1 (step t-1) -> one grid barrier per tick.
//  - Weights bf16, packed once into MFMA B-frag order, held in VGPRs all run.
//  - h state stored bf16 (written by epilogue), c state lives in a register.
//  - SYNC REWORK (this round): all cross-XCD shared data (h buffers, barrier
//    words) accessed via RELAXED agent-scope atomics (sc0|sc1 L1/L2-bypass,
//    coherent at MALL). No __threadfence / no acq-rel => no per-tick
//    buffer_wbl2 / buffer_inv (whole-L2 flush+invalidate) on the critical
//    path. Ordering: producer h-stores drained by __syncthreads' vmcnt(0)
//    before arrival add; root orders counter-resets before gen-bump with an
//    explicit s_waitcnt vmcnt(0).
// ---------------------------------------------------------------------------

#define TT 1024
#define BB 64
#define CC 256
#define HH 512
#define Y_ELEMS (TT * BB * HH)
#define S_ELEMS (BB * HH)

typedef __attribute__((ext_vector_type(8))) short bf16x8;
typedef __attribute__((ext_vector_type(4))) float f32x4;
typedef unsigned int u32;
typedef unsigned short u16;
typedef unsigned long long u64;

// ---- ws layout (bytes) ----
#define WS_BAR 0           // 1024 u32 (barrier lines, 128B-spread)
#define WS_BSUM0 4096      // 2048 f32
#define WS_BSUM1 12288     // 2048 f32
#define WS_H0 20480        // 2 * 32768 u16 (h0 ping-pong, bf16)
#define WS_H1 151552       // 2 * 32768 u16
#define WS_WPK0 282624     // 128*24*64*8 bf16  (layer0 packed W)
#define WS_WPK1 3428352    // 128*32*64*8 bf16  (layer1 packed W)
// end ~ 7.62 MB

__device__ __forceinline__ u16 f2b_rne(float f) {
    u32 u = __float_as_uint(f);
    return (u16)((u + 0x7FFFu + ((u >> 16) & 1u)) >> 16);
}
__device__ __forceinline__ u16 f2b_fast(float f) {  // round-half-up, 2 ops
    return (u16)((__float_as_uint(f) + 0x8000u) >> 16);
}
__device__ __forceinline__ float sigf(float z) { return 1.0f / (1.0f + __expf(-z)); }
__device__ __forceinline__ float tanh_f(float z) { return 2.0f / (1.0f + __expf(-2.0f * z)) - 1.0f; }

__device__ __forceinline__ bf16x8 pack8(float4 a, float4 b) {
    union { u16 u[8]; bf16x8 v; } r;
    r.u[0] = f2b_fast(a.x); r.u[1] = f2b_fast(a.y); r.u[2] = f2b_fast(a.z); r.u[3] = f2b_fast(a.w);
    r.u[4] = f2b_fast(b.x); r.u[5] = f2b_fast(b.y); r.u[6] = f2b_fast(b.z); r.u[7] = f2b_fast(b.w);
    return r.v;
}

// ---- coherence-point (MALL) accessors: relaxed agent scope => sc0|sc1
//      bypass, per-element cross-XCD coherent, NO cache-wide flush/inv ----
__device__ __forceinline__ u64 cload64(const u64* p) {
    return __hip_atomic_load((u64*)p, __ATOMIC_RELAXED, __HIP_MEMORY_SCOPE_AGENT);
}
__device__ __forceinline__ void cstore32(u32* p, u32 v) {
    __hip_atomic_store(p, v, __ATOMIC_RELAXED, __HIP_MEMORY_SCOPE_AGENT);
}
__device__ __forceinline__ u32 cload32(const u32* p) {
    return __hip_atomic_load((u32*)p, __ATOMIC_RELAXED, __HIP_MEMORY_SCOPE_AGENT);
}
__device__ __forceinline__ u32 cadd32(u32* p, u32 v) {
    return __hip_atomic_fetch_add(p, v, __ATOMIC_RELAXED, __HIP_MEMORY_SCOPE_AGENT);
}

// Two-level grid barrier, relaxed-only: 16 groups of 16 blocks -> root -> gen.
// Data visibility: __syncthreads emits s_waitcnt vmcnt(0) (measured, guide) so
// every wave's coherence-point h-stores are complete before thread0's arrival
// add issues. Root orders resets-before-gen-bump with explicit vmcnt(0).
__device__ __forceinline__ void grid_barrier(u32* bar, u32 target) {
    __syncthreads();
    if (threadIdx.x == 0) {
        u32 g = (u32)blockIdx.x >> 4;
        u32 prev = cadd32(&bar[g * 32], 1u);
        if (prev == 15u) {
            u32 p2 = cadd32(&bar[512], 1u);
            if (p2 == 15u) {
                #pragma unroll
                for (int k = 0; k < 16; ++k) cstore32(&bar[k * 32], 0u);
                cstore32(&bar[512], 0u);
                asm volatile("s_waitcnt vmcnt(0)" ::: "memory");  // resets at MALL before gen bump
                cadd32(&bar[544], 1u);
            }
        }
        while (cload32(&bar[544]) < target)
            __builtin_amdgcn_s_sleep(1);
    }
    __syncthreads();
    asm volatile("" ::: "memory");  // no code motion of h loads above the barrier
}

// ---- init: zero barrier, bsum = bih+bhh, h buffers <- bf16(initial h) ----
__global__ void k_init(const float* __restrict__ bih0, const float* __restrict__ bhh0,
                       const float* __restrict__ bih1, const float* __restrict__ bhh1,
                       const float* __restrict__ h00, const float* __restrict__ h01,
                       unsigned char* __restrict__ ws) {
    u32* bar = (u32*)(ws + WS_BAR);
    float* bs0 = (float*)(ws + WS_BSUM0);
    float* bs1 = (float*)(ws + WS_BSUM1);
    u16* h0 = (u16*)(ws + WS_H0);
    u16* h1 = (u16*)(ws + WS_H1);
    int t = blockIdx.x * 256 + threadIdx.x;  // 32768 threads
    if (t < 1024) bar[t] = 0u;
    if (t < 2048) { bs0[t] = bih0[t] + bhh0[t]; bs1[t] = bih1[t] + bhh1[t]; }
    if (t < S_ELEMS) { h0[t] = f2b_rne(h00[t]); h1[t] = f2b_rne(h01[t]); }
}

// ---- weight pack: fp32 [4H,K] -> bf16 B-frag order wpk[bidL][kt][lane][8] ----
// rows permuted: n-index (lane&15) = gg*4+jj  <->  W row = gg*512 + bidL*4 + jj
__global__ void k_wprep(const float* __restrict__ Wih0, const float* __restrict__ Whh0,
                        const float* __restrict__ Wih1, const float* __restrict__ Whh1,
                        unsigned char* __restrict__ ws) {
    u16* wpk0 = (u16*)(ws + WS_WPK0);
    u16* wpk1 = (u16*)(ws + WS_WPK1);
    int u = blockIdx.x * 256 + threadIdx.x;  // 458752 threads
    const float* s;
    u16* d;
    if (u < 128 * 24 * 64) {  // layer0: 8 x-tiles (K=256) + 16 h-tiles (K=512)
        int bidL = u / (24 * 64);
        int kt = (u >> 6) % 24;
        int lane = u & 63;
        int n = lane & 15, quad = lane >> 4;
        int row = (n >> 2) * 512 + bidL * 4 + (n & 3);
        int k = kt * 32 + quad * 8;
        s = (k < 256) ? (Wih0 + (size_t)row * 256 + k) : (Whh0 + (size_t)row * 512 + (k - 256));
        d = wpk0 + (size_t)((bidL * 24 + kt) * 64 + lane) * 8;
    } else {  // layer1: 16 y0-tiles + 16 h1-tiles (K=1024)
        int v = u - 128 * 24 * 64;
        int bidL = v / (32 * 64);
        int kt = (v >> 6) % 32;
        int lane = v & 63;
        int n = lane & 15, quad = lane >> 4;
        int row = (n >> 2) * 512 + bidL * 4 + (n & 3);
        int k = kt * 32 + quad * 8;
        s = (k < 512) ? (Wih1 + (size_t)row * 512 + k) : (Whh1 + (size_t)row * 512 + (k - 512));
        d = wpk1 + (size_t)((bidL * 32 + kt) * 64 + lane) * 8;
    }
    #pragma unroll
    for (int i = 0; i < 8; ++i) d[i] = f2b_rne(s[i]);
}

// ---- the persistent tick loop, templated on layer ----
template <int LAYER>
__device__ void run_ticks(const float* __restrict__ x, const float* __restrict__ c0,
                          float* __restrict__ out, unsigned char* __restrict__ ws, int bidL) {
    constexpr int NKT = (LAYER == 0) ? 24 : 32;
    u32* bar = (u32*)(ws + WS_BAR);
    const float* bs = (const float*)(ws + (LAYER == 0 ? WS_BSUM0 : WS_BSUM1));
    u16* h0b[2] = { (u16*)(ws + WS_H0), (u16*)(ws + WS_H0) + S_ELEMS };
    u16* h1b[2] = { (u16*)(ws + WS_H1), (u16*)(ws + WS_H1) + S_ELEMS };
    const u16* wpk = (const u16*)(ws + (LAYER == 0 ? WS_WPK0 : WS_WPK1));

    const int tid = threadIdx.x, lane = tid & 63, wave = tid >> 6;
    const int r16 = lane & 15, quad = lane >> 4, q8 = quad * 8;
    const int gg = r16 >> 2, jj = r16 & 3;
    const int b0 = wave * 16;
    const int col = bidL * 4 + jj;            // h column this lane finalizes
    const int myb = b0 + quad * 4 + gg;       // batch this lane finalizes
    const int sl0 = (quad << 4) | (0 << 2) | jj;
    const int sl1 = (quad << 4) | (1 << 2) | jj;
    const int sl2 = (quad << 4) | (2 << 2) | jj;
    const int sl3 = (quad << 4) | (3 << 2) | jj;

    // biases (hoisted), c state in register for the whole run
    const float bi = bs[0 * HH + col], bf_ = bs[1 * HH + col];
    const float bg = bs[2 * HH + col], bo = bs[3 * HH + col];
    float c = c0[myb * HH + col];

    // weight fragments: resident in VGPRs for all 1025 ticks
    bf16x8 w[NKT];
    {
        const u16* wp = wpk + (size_t)(bidL * NKT * 64 + lane) * 8;
        #pragma unroll
        for (int kt = 0; kt < NKT; ++kt) w[kt] = *(const bf16x8*)(wp + (size_t)kt * 64 * 8);
    }

    for (int i = 0; i <= TT; ++i) {
        const bool active = (LAYER == 0) ? (i < TT) : (i >= 1);
        const int t = (LAYER == 0) ? i : i - 1;
        if (active) {
            f32x4 aE = {0.f, 0.f, 0.f, 0.f}, aO = {0.f, 0.f, 0.f, 0.f};
            if (LAYER == 0) {
                // x projection: fp32 -> bf16 (half-up) in flight (plain cached loads)
                const float* xp = x + ((size_t)t * BB + b0 + r16) * CC + q8;
                #pragma unroll
                for (int kt = 0; kt < 8; ++kt) {
                    float4 f0 = *(const float4*)(xp + kt * 32);
                    float4 f1 = *(const float4*)(xp + kt * 32 + 4);
                    bf16x8 a = pack8(f0, f1);
                    if (kt & 1) aO = __builtin_amdgcn_mfma_f32_16x16x32_bf16(a, w[kt], aO, 0, 0, 0);
                    else        aE = __builtin_amdgcn_mfma_f32_16x16x32_bf16(a, w[kt], aE, 0, 0, 0);
                }
                // recurrent: h0 (bf16) at buf parity t&1 — coherence-point loads
                const u64* hp = (const u64*)(h0b[t & 1] + (size_t)(b0 + r16) * HH + q8);
                #pragma unroll
                for (int kt = 0; kt < 16; ++kt) {
                    union { u64 q[2]; bf16x8 v; } au;
                    au.q[0] = cload64(hp + kt * 8);
                    au.q[1] = cload64(hp + kt * 8 + 1);
                    if (kt & 1) aO = __builtin_amdgcn_mfma_f32_16x16x32_bf16(au.v, w[8 + kt], aO, 0, 0, 0);
                    else        aE = __builtin_amdgcn_mfma_f32_16x16x32_bf16(au.v, w[8 + kt], aE, 0, 0, 0);
                }
            } else {
                // y0[t] = h0 written at tick t (parity (t+1)&1); h1 prev at t&1
                const u64* pa = (const u64*)(h0b[(t + 1) & 1] + (size_t)(b0 + r16) * HH + q8);
                const u64* pb = (const u64*)(h1b[t & 1] + (size_t)(b0 + r16) * HH + q8);
                #pragma unroll
                for (int kt = 0; kt < 16; ++kt) {
                    union { u64 q[2]; bf16x8 v; } au;
                    au.q[0] = cload64(pa + kt * 8);
                    au.q[1] = cload64(pa + kt * 8 + 1);
                    if (kt & 1) aO = __builtin_amdgcn_mfma_f32_16x16x32_bf16(au.v, w[kt], aO, 0, 0, 0);
                    else        aE = __builtin_amdgcn_mfma_f32_16x16x32_bf16(au.v, w[kt], aE, 0, 0, 0);
                }
                #pragma unroll
                for (int kt = 0; kt < 16; ++kt) {
                    union { u64 q[2]; bf16x8 v; } au;
                    au.q[0] = cload64(pb + kt * 8);
                    au.q[1] = cload64(pb + kt * 8 + 1);
                    if (kt & 1) aO = __builtin_amdgcn_mfma_f32_16x16x32_bf16(au.v, w[16 + kt], aO, 0, 0, 0);
                    else        aE = __builtin_amdgcn_mfma_f32_16x16x32_bf16(au.v, w[16 + kt], aE, 0, 0, 0);
                }
            }
            f32x4 acc = aE + aO;

            // gather the 4 gates for (myb, col): lanes sharing (quad,jj), gg = gate
            float gi = 0.f, gf = 0.f, gc = 0.f, go = 0.f;
            #pragma unroll
            for (int r = 0; r < 4; ++r) {
                float v0 = __shfl(acc[r], sl0, 64);
                float v1 = __shfl(acc[r], sl1, 64);
                float v2 = __shfl(acc[r], sl2, 64);
                float v3 = __shfl(acc[r], sl3, 64);
                if (r == gg) { gi = v0; gf = v1; gc = v2; go = v3; }
            }
            gi = sigf(gi + bi);
            gf = sigf(gf + bf_);
            gc = tanh_f(gc + bg);
            go = sigf(go + bo);
            c = gf * c + gi * gc;
            float h = go * tanh_f(c);

            // h store: pair adjacent-jj lanes into one u32 coherence-point store
            u16* hw = (LAYER == 0) ? h0b[(t + 1) & 1] : h1b[(t + 1) & 1];
            u32 hb = (u32)f2b_rne(h);
            u32 partner = __shfl_xor(hb, 1, 64);
            if ((jj & 1) == 0)
                cstore32((u32*)(hw + (size_t)myb * HH + col), hb | (partner << 16));
            if (LAYER == 1) out[(size_t)t * S_ELEMS + myb * HH + col] = h;
            if (t == TT - 1) {
                float* fin = out + Y_ELEMS + (LAYER == 0 ? 0 : 2) * S_ELEMS;
                fin[myb * HH + col] = h;
                fin[S_ELEMS + myb * HH + col] = c;
            }
        }
        grid_barrier(bar, (u32)(i + 1));
    }
}

__global__ __launch_bounds__(256) void k_lstm(const float* __restrict__ x,
                                              const float* __restrict__ c00,
                                              const float* __restrict__ c01,
                                              float* __restrict__ out,
                                              unsigned char* __restrict__ ws) {
    const int bid = blockIdx.x;
    if (bid < 128) run_ticks<0>(x, c00, out, ws, bid);
    else           run_ticks<1>(x, c01, out, ws, bid - 128);
}

extern "C" void kernel_launch(void* const* d_in, const int* in_sizes, int n_in,
                              void* d_out, int out_size, void* d_ws, size_t ws_size,
                              hipStream_t stream) {
    const float* x    = (const float*)d_in[0];
    const float* h0_0 = (const float*)d_in[1];
    const float* c0_0 = (const float*)d_in[2];
    const float* h0_1 = (const float*)d_in[3];
    const float* c0_1 = (const float*)d_in[4];
    const float* Wih0 = (const float*)d_in[5];
    const float* Whh0 = (const float*)d_in[6];
    const float* bih0 = (const float*)d_in[7];
    const float* bhh0 = (const float*)d_in[8];
    const float* Wih1 = (const float*)d_in[9];
    const float* Whh1 = (const float*)d_in[10];
    const float* bih1 = (const float*)d_in[11];
    const float* bhh1 = (const float*)d_in[12];
    float* out = (float*)d_out;
    unsigned char* ws = (unsigned char*)d_ws;

    k_init<<<128, 256, 0, stream>>>(bih0, bhh0, bih1, bhh1, h0_0, h0_1, ws);
    k_wprep<<<1792, 256, 0, stream>>>(Wih0, Whh0, Wih1, Whh1, ws);
    k_lstm<<<256, 256, 0, stream>>>(x, c0_0, c0_1, out, ws);
}